// Round 1
// baseline (384.740 us; speedup 1.0000x reference)
//
#include <hip/hip_runtime.h>

// HCEN forward: out = (mean_S(x) @ W_enc^T + b_enc) @ W_out^T + b_out
// B=16, S=4096, D_IN=H=D_OUT=1024, all fp32.

#define B_     16
#define S_     4096
#define DIN_   1024
#define H_     1024
#define DOUT_  1024
#define SSPLIT 64              // s-chunks per batch row
#define SCHUNK (S_ / SSPLIT)   // 64 rows per block

// ---------------------------------------------------------------------------
// Kernel 1: partial sums over S.
// grid = B_*SSPLIT blocks, 256 threads. Thread t owns float4 column d=[4t,4t+4).
// Reads are fully coalesced: 256 threads x 16 B = 4 KB contiguous per row.
// ---------------------------------------------------------------------------
__global__ __launch_bounds__(256) void mean_partial(
    const float* __restrict__ x, float* __restrict__ part) {
  const int blk = blockIdx.x;           // b * SSPLIT + sc
  const int b   = blk >> 6;             // / SSPLIT
  const int sc  = blk & (SSPLIT - 1);
  const int tid = threadIdx.x;

  const float4* xb = (const float4*)(x + (size_t)b * S_ * DIN_ +
                                         (size_t)sc * SCHUNK * DIN_);
  float4 acc = make_float4(0.f, 0.f, 0.f, 0.f);
#pragma unroll 4
  for (int s = 0; s < SCHUNK; ++s) {
    float4 v = xb[(size_t)s * (DIN_ / 4) + tid];
    acc.x += v.x; acc.y += v.y; acc.z += v.z; acc.w += v.w;
  }
  ((float4*)(part + (size_t)blk * DIN_))[tid] = acc;
}

// ---------------------------------------------------------------------------
// Kernel 2: finish mean. part is [B_*SSPLIT][DIN_]; m is [B_][DIN_].
// grid*block covers B_*DIN_/4 float4 elements.
// ---------------------------------------------------------------------------
__global__ __launch_bounds__(256) void mean_finish(
    const float* __restrict__ part, float* __restrict__ m) {
  const int idx = blockIdx.x * 256 + threadIdx.x;  // float4 index in [0, B_*DIN_/4)
  const int b   = idx / (DIN_ / 4);
  const int dd  = idx % (DIN_ / 4);

  float4 acc = make_float4(0.f, 0.f, 0.f, 0.f);
#pragma unroll 8
  for (int sc = 0; sc < SSPLIT; ++sc) {
    float4 v = ((const float4*)part)[(size_t)(b * SSPLIT + sc) * (DIN_ / 4) + dd];
    acc.x += v.x; acc.y += v.y; acc.z += v.z; acc.w += v.w;
  }
  const float inv = 1.0f / (float)S_;
  acc.x *= inv; acc.y *= inv; acc.z *= inv; acc.w *= inv;
  ((float4*)m)[idx] = acc;
}

// ---------------------------------------------------------------------------
// Kernels 3/4: dense layer  out[b][h] = dot(in[b][:K], W[h][:K]) + bias[h]
// K = 1024 fixed. One block per h; thread t loads W[h] float4 slice once and
// dots it against all B_=16 input rows; wave shuffle-reduce + LDS combine.
// ---------------------------------------------------------------------------
__global__ __launch_bounds__(256) void dense1024(
    const float* __restrict__ in, const float* __restrict__ W,
    const float* __restrict__ bias, float* __restrict__ out) {
  const int h   = blockIdx.x;
  const int tid = threadIdx.x;          // 0..255 == K/4
  const int lane = tid & 63;
  const int wave = tid >> 6;

  const float4 wv = ((const float4*)(W + (size_t)h * 1024))[tid];

  float acc[B_];
#pragma unroll
  for (int b = 0; b < B_; ++b) {
    float4 v = ((const float4*)(in + (size_t)b * 1024))[tid];
    acc[b] = v.x * wv.x + v.y * wv.y + v.z * wv.z + v.w * wv.w;
  }

  // wave-level reduce (64 lanes)
#pragma unroll
  for (int b = 0; b < B_; ++b) {
#pragma unroll
    for (int off = 32; off > 0; off >>= 1)
      acc[b] += __shfl_down(acc[b], off, 64);
  }

  __shared__ float red[B_][4];
  if (lane == 0) {
#pragma unroll
    for (int b = 0; b < B_; ++b) red[b][wave] = acc[b];
  }
  __syncthreads();

  if (tid < B_) {
    float r = red[tid][0] + red[tid][1] + red[tid][2] + red[tid][3] + bias[h];
    out[(size_t)tid * gridDim.x + h] = r;
  }
}

extern "C" void kernel_launch(void* const* d_in, const int* in_sizes, int n_in,
                              void* d_out, int out_size, void* d_ws, size_t ws_size,
                              hipStream_t stream) {
  const float* x     = (const float*)d_in[0];  // [B,S,DIN]
  const float* W_enc = (const float*)d_in[1];  // [H,DIN]
  const float* b_enc = (const float*)d_in[2];  // [H]
  const float* W_out = (const float*)d_in[3];  // [DOUT,H]
  const float* b_out = (const float*)d_in[4];  // [DOUT]
  float* out = (float*)d_out;                  // [B,DOUT]

  // workspace layout
  float* part = (float*)d_ws;                        // B_*SSPLIT*DIN_ = 4 MB
  float* m    = part + (size_t)B_ * SSPLIT * DIN_;   // B_*DIN_
  float* enc  = m + (size_t)B_ * DIN_;               // B_*H_

  mean_partial<<<B_ * SSPLIT, 256, 0, stream>>>(x, part);
  mean_finish<<<(B_ * DIN_ / 4) / 256, 256, 0, stream>>>(part, m);
  dense1024<<<H_, 256, 0, stream>>>(m, W_enc, b_enc, enc);
  dense1024<<<DOUT_, 256, 0, stream>>>(enc, W_out, b_out, out);
}

// Round 2
// 364.424 us; speedup vs baseline: 1.0557x; 1.0557x over previous
//
#include <hip/hip_runtime.h>

// HCEN forward: out = (mean_S(x) @ W_enc^T + b_enc) @ W_out^T + b_out
// B=16, S=4096, D_IN=H=D_OUT=1024, all fp32.
// Memory-bound on streaming x once (268 MB). GEMVs are tiny (67 MFLOP total).

#define B_     16
#define S_     4096
#define DIN_   1024
#define H_     1024
#define DOUT_  1024
#define SSPLIT 128             // s-chunks per batch row
#define SCHUNK (S_ / SSPLIT)   // 32 rows per block

typedef float v4f __attribute__((ext_vector_type(4)));

// ---------------------------------------------------------------------------
// Kernel 1: partial sums over S.
// grid = B_*SSPLIT = 2048 blocks, 256 threads. Thread t owns float4 column
// d = [4t, 4t+4). Per-row reads are fully coalesced (256 x 16 B = 4 KB).
// Nontemporal: x is streamed exactly once, no reuse.
// ---------------------------------------------------------------------------
__global__ __launch_bounds__(256) void mean_partial(
    const float* __restrict__ x, float* __restrict__ part) {
  const int blk = blockIdx.x;            // b * SSPLIT + sc
  const int b   = blk >> 7;              // / SSPLIT
  const int sc  = blk & (SSPLIT - 1);
  const int tid = threadIdx.x;

  const v4f* xb = (const v4f*)(x + (size_t)b * S_ * DIN_ +
                                   (size_t)sc * SCHUNK * DIN_);
  v4f a0 = 0.f, a1 = 0.f, a2 = 0.f, a3 = 0.f;
#pragma unroll
  for (int s = 0; s < SCHUNK; s += 4) {
    v4f v0 = __builtin_nontemporal_load(&xb[(size_t)(s + 0) * (DIN_ / 4) + tid]);
    v4f v1 = __builtin_nontemporal_load(&xb[(size_t)(s + 1) * (DIN_ / 4) + tid]);
    v4f v2 = __builtin_nontemporal_load(&xb[(size_t)(s + 2) * (DIN_ / 4) + tid]);
    v4f v3 = __builtin_nontemporal_load(&xb[(size_t)(s + 3) * (DIN_ / 4) + tid]);
    a0 += v0; a1 += v1; a2 += v2; a3 += v3;
  }
  ((v4f*)(part + (size_t)blk * DIN_))[tid] = (a0 + a1) + (a2 + a3);
}

// ---------------------------------------------------------------------------
// Kernel 2: finish mean. part is [B_*SSPLIT][DIN_]; m is [B_][DIN_].
// 16 blocks x 256 threads cover B_*DIN_/4 = 4096 float4 elements.
// ---------------------------------------------------------------------------
__global__ __launch_bounds__(256) void mean_finish(
    const float* __restrict__ part, float* __restrict__ m) {
  const int idx = blockIdx.x * 256 + threadIdx.x;  // float4 index
  const int b   = idx >> 8;                        // / (DIN_/4)
  const int dd  = idx & 255;

  const v4f* p = (const v4f*)part;
  v4f a0 = 0.f, a1 = 0.f;
#pragma unroll 8
  for (int sc = 0; sc < SSPLIT; sc += 2) {
    a0 += p[(size_t)(b * SSPLIT + sc)     * (DIN_ / 4) + dd];
    a1 += p[(size_t)(b * SSPLIT + sc + 1) * (DIN_ / 4) + dd];
  }
  ((v4f*)m)[idx] = (a0 + a1) * (1.0f / (float)S_);
}

// ---------------------------------------------------------------------------
// Kernels 3/4: dense layer  out[b][h] = dot(in[b][:1024], W[h][:1024]) + bias[h]
// One block per h; thread t loads W[h] float4 slice once and dots it against
// all B_=16 input rows (L2-resident, 64 KB); shuffle + LDS reduce.
// ---------------------------------------------------------------------------
__global__ __launch_bounds__(256) void dense1024(
    const float* __restrict__ in, const float* __restrict__ W,
    const float* __restrict__ bias, float* __restrict__ out) {
  const int h    = blockIdx.x;
  const int tid  = threadIdx.x;          // 0..255 == K/4
  const int lane = tid & 63;
  const int wave = tid >> 6;

  const v4f wv = __builtin_nontemporal_load(&((const v4f*)(W + (size_t)h * 1024))[tid]);

  float acc[B_];
#pragma unroll
  for (int b = 0; b < B_; ++b) {
    v4f v = ((const v4f*)(in + (size_t)b * 1024))[tid];
    v4f pr = v * wv;
    acc[b] = (pr[0] + pr[1]) + (pr[2] + pr[3]);
  }

#pragma unroll
  for (int b = 0; b < B_; ++b) {
#pragma unroll
    for (int off = 32; off > 0; off >>= 1)
      acc[b] += __shfl_down(acc[b], off, 64);
  }

  __shared__ float red[B_][4];
  if (lane == 0) {
#pragma unroll
    for (int b = 0; b < B_; ++b) red[b][wave] = acc[b];
  }
  __syncthreads();

  if (tid < B_) {
    float r = red[tid][0] + red[tid][1] + red[tid][2] + red[tid][3] + bias[h];
    out[(size_t)tid * gridDim.x + h] = r;
  }
}

extern "C" void kernel_launch(void* const* d_in, const int* in_sizes, int n_in,
                              void* d_out, int out_size, void* d_ws, size_t ws_size,
                              hipStream_t stream) {
  const float* x     = (const float*)d_in[0];  // [B,S,DIN]
  const float* W_enc = (const float*)d_in[1];  // [H,DIN]
  const float* b_enc = (const float*)d_in[2];  // [H]
  const float* W_out = (const float*)d_in[3];  // [DOUT,H]
  const float* b_out = (const float*)d_in[4];  // [DOUT]
  float* out = (float*)d_out;                  // [B,DOUT]

  float* part = (float*)d_ws;                        // B_*SSPLIT*DIN_ = 8 MB
  float* m    = part + (size_t)B_ * SSPLIT * DIN_;   // B_*DIN_
  float* enc  = m + (size_t)B_ * DIN_;               // B_*H_

  mean_partial<<<B_ * SSPLIT, 256, 0, stream>>>(x, part);
  mean_finish<<<(B_ * DIN_ / 4) / 256, 256, 0, stream>>>(part, m);
  dense1024<<<H_, 256, 0, stream>>>(m, W_enc, b_enc, enc);
  dense1024<<<DOUT_, 256, 0, stream>>>(enc, W_out, b_out, out);
}

// Round 3
// 358.652 us; speedup vs baseline: 1.0727x; 1.0161x over previous
//
#include <hip/hip_runtime.h>

// HCEN forward: out = (mean_S(x) @ W_enc^T + b_enc) @ W_out^T + b_out
// B=16, S=4096, D_IN=H=D_OUT=1024, all fp32.
// Memory-bound on streaming x once (268 MB -> ~43 us @ 6.3 TB/s).
// GEMVs are tiny (67 MFLOP total, 8 MB weights).

#define B_     16
#define S_     4096
#define DIN_   1024
#define H_     1024
#define DOUT_  1024
#define SSPLIT 64              // s-chunks per batch row
#define SCHUNK (S_ / SSPLIT)   // 64 rows per block

typedef float v4f __attribute__((ext_vector_type(4)));

// ---------------------------------------------------------------------------
// Kernel 1: partial sums over S.
// grid = B_*SSPLIT = 1024 blocks (4/CU), 256 threads. Thread t owns float4
// column d=[4t,4t+4). Per-row reads fully coalesced (256 x 16 B = 4 KB).
// 8 independent accumulators -> 8 outstanding nontemporal loads per lane.
// ---------------------------------------------------------------------------
__global__ __launch_bounds__(256) void mean_partial(
    const float* __restrict__ x, float* __restrict__ part) {
  const int blk = blockIdx.x;            // b * SSPLIT + sc
  const int b   = blk >> 6;              // / SSPLIT
  const int sc  = blk & (SSPLIT - 1);
  const int tid = threadIdx.x;

  const v4f* xb = (const v4f*)(x + (size_t)b * S_ * DIN_ +
                                   (size_t)sc * SCHUNK * DIN_);
  v4f a0 = 0.f, a1 = 0.f, a2 = 0.f, a3 = 0.f;
  v4f a4 = 0.f, a5 = 0.f, a6 = 0.f, a7 = 0.f;
#pragma unroll
  for (int s = 0; s < SCHUNK; s += 8) {
    v4f v0 = __builtin_nontemporal_load(&xb[(size_t)(s + 0) * 256 + tid]);
    v4f v1 = __builtin_nontemporal_load(&xb[(size_t)(s + 1) * 256 + tid]);
    v4f v2 = __builtin_nontemporal_load(&xb[(size_t)(s + 2) * 256 + tid]);
    v4f v3 = __builtin_nontemporal_load(&xb[(size_t)(s + 3) * 256 + tid]);
    v4f v4 = __builtin_nontemporal_load(&xb[(size_t)(s + 4) * 256 + tid]);
    v4f v5 = __builtin_nontemporal_load(&xb[(size_t)(s + 5) * 256 + tid]);
    v4f v6 = __builtin_nontemporal_load(&xb[(size_t)(s + 6) * 256 + tid]);
    v4f v7 = __builtin_nontemporal_load(&xb[(size_t)(s + 7) * 256 + tid]);
    a0 += v0; a1 += v1; a2 += v2; a3 += v3;
    a4 += v4; a5 += v5; a6 += v6; a7 += v7;
  }
  ((v4f*)(part + (size_t)blk * DIN_))[tid] =
      ((a0 + a1) + (a2 + a3)) + ((a4 + a5) + (a6 + a7));
}

// ---------------------------------------------------------------------------
// Kernel 2: finish mean. part is [B_*SSPLIT][DIN_]; m is [B_][DIN_].
// 16 blocks x 256 threads cover B_*DIN_/4 = 4096 float4 elements. 4 MB read.
// ---------------------------------------------------------------------------
__global__ __launch_bounds__(256) void mean_finish(
    const float* __restrict__ part, float* __restrict__ m) {
  const int idx = blockIdx.x * 256 + threadIdx.x;  // float4 index
  const int b   = idx >> 8;                        // / (DIN_/4)
  const int dd  = idx & 255;

  const v4f* p = (const v4f*)part;
  v4f a0 = 0.f, a1 = 0.f;
#pragma unroll 8
  for (int sc = 0; sc < SSPLIT; sc += 2) {
    a0 += p[(size_t)(b * SSPLIT + sc)     * 256 + dd];
    a1 += p[(size_t)(b * SSPLIT + sc + 1) * 256 + dd];
  }
  ((v4f*)m)[idx] = (a0 + a1) * (1.0f / (float)S_);
}

// ---------------------------------------------------------------------------
// Kernels 3/4: dense layer  out[b][h] = dot(in[b][:1024], W[h][:1024]) + bias[h]
// One block per h; thread t loads W[h] float4 slice once (streamed, nt) and
// dots against all B_=16 input rows (L2-resident, 64 KB); shuffle+LDS reduce.
// ---------------------------------------------------------------------------
__global__ __launch_bounds__(256) void dense1024(
    const float* __restrict__ in, const float* __restrict__ W,
    const float* __restrict__ bias, float* __restrict__ out) {
  const int h    = blockIdx.x;
  const int tid  = threadIdx.x;          // 0..255 == K/4
  const int lane = tid & 63;
  const int wave = tid >> 6;

  const v4f wv = __builtin_nontemporal_load(&((const v4f*)(W + (size_t)h * 1024))[tid]);

  float acc[B_];
#pragma unroll
  for (int b = 0; b < B_; ++b) {
    v4f v = ((const v4f*)(in + (size_t)b * 1024))[tid];
    v4f pr = v * wv;
    acc[b] = (pr[0] + pr[1]) + (pr[2] + pr[3]);
  }

#pragma unroll
  for (int b = 0; b < B_; ++b) {
#pragma unroll
    for (int off = 32; off > 0; off >>= 1)
      acc[b] += __shfl_down(acc[b], off, 64);
  }

  __shared__ float red[B_][4];
  if (lane == 0) {
#pragma unroll
    for (int b = 0; b < B_; ++b) red[b][wave] = acc[b];
  }
  __syncthreads();

  if (tid < B_) {
    float r = red[tid][0] + red[tid][1] + red[tid][2] + red[tid][3] + bias[h];
    out[(size_t)tid * gridDim.x + h] = r;
  }
}

extern "C" void kernel_launch(void* const* d_in, const int* in_sizes, int n_in,
                              void* d_out, int out_size, void* d_ws, size_t ws_size,
                              hipStream_t stream) {
  const float* x     = (const float*)d_in[0];  // [B,S,DIN]
  const float* W_enc = (const float*)d_in[1];  // [H,DIN]
  const float* b_enc = (const float*)d_in[2];  // [H]
  const float* W_out = (const float*)d_in[3];  // [DOUT,H]
  const float* b_out = (const float*)d_in[4];  // [DOUT]
  float* out = (float*)d_out;                  // [B,DOUT]

  float* part = (float*)d_ws;                        // B_*SSPLIT*DIN_ = 4 MB
  float* m    = part + (size_t)B_ * SSPLIT * DIN_;   // B_*DIN_
  float* enc  = m + (size_t)B_ * DIN_;               // B_*H_

  mean_partial<<<B_ * SSPLIT, 256, 0, stream>>>(x, part);
  mean_finish<<<(B_ * DIN_ / 4) / 256, 256, 0, stream>>>(part, m);
  dense1024<<<H_, 256, 0, stream>>>(m, W_enc, b_enc, enc);
  dense1024<<<DOUT_, 256, 0, stream>>>(enc, W_out, b_out, out);
}